// Round 5
// baseline (188.757 us; speedup 1.0000x reference)
//
#include <hip/hip_runtime.h>
#include <hip/hip_bf16.h>

#define NLEAF 256
#define MBLK 256
#define THREADS 256

typedef __attribute__((ext_vector_type(4))) float f32x4;
typedef __attribute__((ext_vector_type(4))) unsigned int uint4v;
typedef __attribute__((ext_vector_type(8))) __bf16 bf16x8;
typedef __attribute__((ext_vector_type(4))) __bf16 bf16x4;

// LDS layout (bytes)
#define OFF_DIST 0        // 131072: dist bf16 [256 leaves][256 rows]
#define OFF_XP   131072   // 16384 : x-stage f32 chunk / P-level ping-pong
#define OFF_AC   147456   // 1024  : A_c[255] f32
#define OFF_BC   148480   // 1024  : B_c[255] f32
#define OFF_ANG  149504   // 1024  : angles[256] f32
#define OFF_RAY  150528   // 256   : ray[64] f32
#define SMEM_BYTES 150784

__device__ __forceinline__ float sigf(float s) { return 1.0f / (1.0f + __expf(-s)); }

// Pre-pass: T fp32 [l][k(64)][w(32)] -> bf16 ws in MFMA FRAGMENT ORDER:
// frag f = (k>>5)*2 + (w>>4); lane = ((k>>3)&3)*16 + (w&15); byte j = (k&7)*2.
// addr = l*4096 + f*1024 + lane*16 + j*2.
// LDS-transpose so global reads AND writes stay fully coalesced.
__global__ __launch_bounds__(256) void prep_T(const float* __restrict__ T,
                                              __bf16* __restrict__ wsT) {
  __shared__ char tile[4096];
  const int l = blockIdx.x;
  const float* src = T + (size_t)l * 2048;
  const int t = threadIdx.x;
#pragma unroll
  for (int p = 0; p < 2; ++p) {
    int e = p * 1024 + t * 4;  // element within leaf: k = e>>5, w = e&31
    f32x4 v = *(const f32x4*)(src + e);
    int k = e >> 5, w0 = e & 31;
#pragma unroll
    for (int j = 0; j < 4; ++j) {
      int w = w0 + j;
      int off = ((k >> 5) * 2 + (w >> 4)) * 1024 +
                (((k >> 3) & 3) * 16 + (w & 15)) * 16 + (k & 7) * 2;
      *(__bf16*)(tile + off) = (__bf16)v[j];
    }
  }
  __syncthreads();
  *(uint4v*)((char*)wsT + (size_t)l * 4096 + t * 16) = *(const uint4v*)(tile + t * 16);
}

template <bool USE_WS>
__global__ __launch_bounds__(THREADS, 1)
void prl_main(const float* __restrict__ x, const float* __restrict__ ray,
              const float* __restrict__ w_i, const float* __restrict__ b_i,
              const float* __restrict__ a_i, const void* __restrict__ tsrc,
              float* __restrict__ out) {
  extern __shared__ char smem[];
  const int tid = threadIdx.x;
  const int lane = tid & 63;
  const int wid = tid >> 6;   // 4 waves; wave owns rows [wid*64, wid*64+64)
  const int g = lane >> 4;
  const int ln = lane & 15;
  const int row0 = blockIdx.x * MBLK;

  float* A_c = (float*)(smem + OFF_AC);
  float* B_c = (float*)(smem + OFF_BC);
  float* angles = (float*)(smem + OFF_ANG);
  float* ray_l = (float*)(smem + OFF_RAY);
  __bf16* distb = (__bf16*)(smem + OFF_DIST);

  // ---- stage node constants + ray ----
  if (tid < 255) {
    float aa = 1.0f + a_i[tid];
    A_c[tid] = (0.5f + sigf(w_i[tid])) * aa;
    B_c[tid] = -sigf(b_i[tid]) * aa;
  }
  if (tid < 64) ray_l[tid] = ray[tid];
  __syncthreads();

  // ---- x staging (4 chunks of 64 rows), angles, A-fragment extraction ----
  bf16x8 afrag[4][2] = {};
  float* xp = (float*)(smem + OFF_XP);
  for (int c = 0; c < 4; ++c) {
    const float* xg = x + (size_t)(row0 + c * 64) * 64;
#pragma unroll
    for (int p = 0; p < 4; ++p) {
      int idx = p * 256 + tid;  // float4 slot 0..1023 in chunk
      f32x4 v = *(const f32x4*)(xg + idx * 4);
      *(f32x4*)(xp + idx * 4) = v;
      int cg = idx & 15;
      f32x4 rv = *(const f32x4*)(ray_l + cg * 4);
      float a0 = v[0] * v[0] + v[1] * v[1] + v[2] * v[2] + v[3] * v[3];
      float a1 = v[0] * rv[0] + v[1] * rv[1] + v[2] * rv[2] + v[3] * rv[3];
      float a2 = rv[0] * rv[0] + rv[1] * rv[1] + rv[2] * rv[2] + rv[3] * rv[3];
#pragma unroll
      for (int s = 1; s < 16; s <<= 1) {
        a0 += __shfl_xor(a0, s, 64);
        a1 += __shfl_xor(a1, s, 64);
        a2 += __shfl_xor(a2, s, 64);
      }
      if ((tid & 15) == 0) {
        int r = idx >> 4;
        float xn = fmaxf(sqrtf(a0), 1e-8f);
        float rn = fmaxf(sqrtf(a2), 1e-8f);
        float cs = a1 / (xn * rn);
        cs = fminf(fmaxf(cs, -1.0f), 1.0f);
        angles[c * 64 + r] = acosf(cs) * 0.31830988618379067f;
      }
    }
    __syncthreads();
    if (wid == c) {  // wave c owns this chunk's 64 rows
#pragma unroll
      for (int mt = 0; mt < 4; ++mt)
#pragma unroll
        for (int kt = 0; kt < 2; ++kt) {
          int rl = mt * 16 + ln;
          int k0 = kt * 32 + g * 8;
          f32x4 u0 = *(const f32x4*)(xp + rl * 64 + k0);
          f32x4 u1 = *(const f32x4*)(xp + rl * 64 + k0 + 4);
          bf16x8 af;
          af[0] = (__bf16)u0[0]; af[1] = (__bf16)u0[1];
          af[2] = (__bf16)u0[2]; af[3] = (__bf16)u0[3];
          af[4] = (__bf16)u1[0]; af[5] = (__bf16)u1[1];
          af[6] = (__bf16)u1[2]; af[7] = (__bf16)u1[3];
          afrag[mt][kt] = af;
        }
    }
    __syncthreads();
  }

  // ---- tree probabilities (level passes, bf16, ping-pong in dead x region) ----
  __bf16* PA = (__bf16*)(smem + OFF_XP);
  __bf16* PB = (__bf16*)(smem + OFF_XP + 8192);
  {  // P0 -> P1 (512)
    float ang = angles[tid];
    float d = sigf(fmaf(A_c[0], ang, B_c[0]));
    PA[tid] = (__bf16)d;
    PA[256 + tid] = (__bf16)(1.0f - d);
  }
  __syncthreads();
#pragma unroll
  for (int it = 0; it < 2; ++it) {  // P1 (512) -> P2 (1024)
    int e = it * 256 + tid;
    int n = e >> 8, r = e & 255;
    float p = (float)PA[e];
    float ang = angles[r];
    float d = sigf(fmaf(A_c[1 + n], ang, B_c[1 + n]));
    PB[(2 * n) * 256 + r] = (__bf16)(p * d);
    PB[(2 * n + 1) * 256 + r] = (__bf16)(p * (1.0f - d));
  }
  __syncthreads();
#pragma unroll
  for (int it = 0; it < 4; ++it) {  // P2 (1024) -> P3 (2048)
    int e = it * 256 + tid;
    int n = e >> 8, r = e & 255;
    float p = (float)PB[e];
    float ang = angles[r];
    float d = sigf(fmaf(A_c[3 + n], ang, B_c[3 + n]));
    PA[(2 * n) * 256 + r] = (__bf16)(p * d);
    PA[(2 * n + 1) * 256 + r] = (__bf16)(p * (1.0f - d));
  }
  __syncthreads();
#pragma unroll
  for (int it = 0; it < 8; ++it) {  // P3 (2048) -> P4 (4096)
    int e = it * 256 + tid;
    int n = e >> 8, r = e & 255;
    float p = (float)PA[e];
    float ang = angles[r];
    float d = sigf(fmaf(A_c[7 + n], ang, B_c[7 + n]));
    PB[(2 * n) * 256 + r] = (__bf16)(p * d);
    PB[(2 * n + 1) * 256 + r] = (__bf16)(p * (1.0f - d));
  }
  __syncthreads();
#pragma unroll
  for (int it = 0; it < 16; ++it) {  // P4 -> fused levels 4..7 -> dist
    int e = it * 256 + tid;
    int n4 = e >> 8, r = e & 255;
    float p4 = (float)PB[e];
    float ang = angles[r];
    float d4 = sigf(fmaf(A_c[15 + n4], ang, B_c[15 + n4]));
    float p5[2] = {p4 * d4, p4 * (1.0f - d4)};
#pragma unroll
    for (int b5 = 0; b5 < 2; ++b5) {
      int n5 = 2 * n4 + b5;
      float d5 = sigf(fmaf(A_c[31 + n5], ang, B_c[31 + n5]));
      float p6[2] = {p5[b5] * d5, p5[b5] * (1.0f - d5)};
#pragma unroll
      for (int b6 = 0; b6 < 2; ++b6) {
        int n6 = 2 * n5 + b6;
        float d6 = sigf(fmaf(A_c[63 + n6], ang, B_c[63 + n6]));
        float p7[2] = {p6[b6] * d6, p6[b6] * (1.0f - d6)};
#pragma unroll
        for (int b7 = 0; b7 < 2; ++b7) {
          int n7 = 2 * n6 + b7;
          float d7 = sigf(fmaf(A_c[127 + n7], ang, B_c[127 + n7]));
          float pv = p7[b7];
          distb[(2 * n7) * 256 + r] = (__bf16)(pv * d7);
          distb[(2 * n7 + 1) * 256 + r] = (__bf16)(pv * (1.0f - d7));
        }
      }
    }
  }
  __syncthreads();  // dist complete; NO barriers after this point

  // ---- leaf loop: B direct global->VGPR (fragment order), 4-deep prefetch,
  //      barrier-free. dist via broadcast ds_read_b64. ----
  f32x4 acc[4][2] = {};
  const char* bp = (const char*)tsrc + lane * 16;

  auto step = [&](const bf16x8 (&bv)[4], int l) {
    f32x4 dv[4];
#pragma unroll
    for (int mt = 0; mt < 4; ++mt) {
      bf16x4 dd = *(const bf16x4*)(distb + l * 256 + wid * 64 + mt * 16 + g * 4);
      dv[mt] = (f32x4){(float)dd[0], (float)dd[1], (float)dd[2], (float)dd[3]};
    }
    f32x4 zero = {0.0f, 0.0f, 0.0f, 0.0f};
#pragma unroll
    for (int mt = 0; mt < 4; ++mt)
#pragma unroll
      for (int nt = 0; nt < 2; ++nt) {
        bf16x8 bk0, bk1;
        if constexpr (USE_WS) {
          bk0 = bv[nt];      // frag f = 0*2+nt
          bk1 = bv[2 + nt];  // frag f = 1*2+nt
        } else {
          const float* tp0 = (const float*)tsrc + (size_t)l * 2048 + (g * 8) * 32 + nt * 16 + ln;
          const float* tp1 = tp0 + 32 * 32;
#pragma unroll
          for (int j = 0; j < 8; ++j) {
            bk0[j] = (__bf16)tp0[j * 32];
            bk1[j] = (__bf16)tp1[j * 32];
          }
        }
        f32x4 y = __builtin_amdgcn_mfma_f32_16x16x32_bf16(afrag[mt][0], bk0, zero, 0, 0, 0);
        y = __builtin_amdgcn_mfma_f32_16x16x32_bf16(afrag[mt][1], bk1, y, 0, 0, 0);
        acc[mt][nt] += dv[mt] * y;
      }
  };

  if constexpr (USE_WS) {
    bf16x8 b0[4], b1[4], b2[4], b3[4];
#pragma unroll
    for (int f = 0; f < 4; ++f) {
      b0[f] = *(const bf16x8*)(bp + 0 * 4096 + f * 1024);
      b1[f] = *(const bf16x8*)(bp + 1 * 4096 + f * 1024);
      b2[f] = *(const bf16x8*)(bp + 2 * 4096 + f * 1024);
      b3[f] = *(const bf16x8*)(bp + 3 * 4096 + f * 1024);
    }
    for (int l = 0; l < NLEAF; l += 4) {
      step(b0, l);
      if (l + 4 < NLEAF) {
        const char* q = bp + (size_t)(l + 4) * 4096;
#pragma unroll
        for (int f = 0; f < 4; ++f) b0[f] = *(const bf16x8*)(q + f * 1024);
      }
      step(b1, l + 1);
      if (l + 5 < NLEAF) {
        const char* q = bp + (size_t)(l + 5) * 4096;
#pragma unroll
        for (int f = 0; f < 4; ++f) b1[f] = *(const bf16x8*)(q + f * 1024);
      }
      step(b2, l + 2);
      if (l + 6 < NLEAF) {
        const char* q = bp + (size_t)(l + 6) * 4096;
#pragma unroll
        for (int f = 0; f < 4; ++f) b2[f] = *(const bf16x8*)(q + f * 1024);
      }
      step(b3, l + 3);
      if (l + 7 < NLEAF) {
        const char* q = bp + (size_t)(l + 7) * 4096;
#pragma unroll
        for (int f = 0; f < 4; ++f) b3[f] = *(const bf16x8*)(q + f * 1024);
      }
    }
  } else {
    bf16x8 dummy[4] = {};
    for (int l = 0; l < NLEAF; ++l) step(dummy, l);
  }

  // ---- epilogue: C/D layout col=lane&15, row=(lane>>4)*4+reg ----
#pragma unroll
  for (int mt = 0; mt < 4; ++mt)
#pragma unroll
    for (int nt = 0; nt < 2; ++nt)
#pragma unroll
      for (int e = 0; e < 4; ++e) {
        int row = row0 + wid * 64 + mt * 16 + g * 4 + e;
        out[(size_t)row * 32 + nt * 16 + ln] = acc[mt][nt][e];
      }
}

extern "C" void kernel_launch(void* const* d_in, const int* in_sizes, int n_in,
                              void* d_out, int out_size, void* d_ws, size_t ws_size,
                              hipStream_t stream) {
  const float* x = (const float*)d_in[0];
  const float* ray = (const float*)d_in[1];
  const float* T = (const float*)d_in[2];
  const float* w_i = (const float*)d_in[3];
  const float* b_i = (const float*)d_in[4];
  const float* a_i = (const float*)d_in[5];
  float* out = (float*)d_out;

  bool use_ws = ws_size >= (size_t)NLEAF * 4096;
  if (use_ws) {
    hipFuncSetAttribute(reinterpret_cast<const void*>(&prl_main<true>),
                        hipFuncAttributeMaxDynamicSharedMemorySize, SMEM_BYTES);
    prep_T<<<256, 256, 0, stream>>>(T, (__bf16*)d_ws);
    prl_main<true><<<256, THREADS, SMEM_BYTES, stream>>>(x, ray, w_i, b_i, a_i, d_ws, out);
  } else {
    hipFuncSetAttribute(reinterpret_cast<const void*>(&prl_main<false>),
                        hipFuncAttributeMaxDynamicSharedMemorySize, SMEM_BYTES);
    prl_main<false><<<256, THREADS, SMEM_BYTES, stream>>>(x, ray, w_i, b_i, a_i, T, out);
  }
}

// Round 6
// 174.567 us; speedup vs baseline: 1.0813x; 1.0813x over previous
//
#include <hip/hip_runtime.h>
#include <hip/hip_bf16.h>

#define NLEAF 256
#define MBLK 256
#define THREADS 512

typedef __attribute__((ext_vector_type(4))) float f32x4;
typedef __attribute__((ext_vector_type(4))) unsigned int uint4v;
typedef __attribute__((ext_vector_type(8))) __bf16 bf16x8;
typedef __attribute__((ext_vector_type(4))) __bf16 bf16x4;

// LDS layout (bytes)
#define OFF_DIST 0        // 131072: dist bf16 [256 leaves][256 perm-rows]
#define OFF_XP   131072   // 16384 : x-stage / tree ping-pong / T dbuf (2x8KB)
#define OFF_AC   147456   // 1024  : A_c[255] f32
#define OFF_BC   148480   // 1024  : B_c[255] f32
#define OFF_ANG  149504   // 1024  : angles[256] f32
#define OFF_RAY  150528   // 256   : ray[64] f32
#define SMEM_BYTES 150784

__device__ __forceinline__ float sigf(float s) { return 1.0f / (1.0f + __expf(-s)); }

// row permutation for dist: r = rg[7:6]|mt[5:4]|g[3:2]|e[1:0] -> rg|g|mt|e
__device__ __forceinline__ int permr(int r) {
  return (r & 0xC3) | ((r & 0x30) >> 2) | ((r & 0x0C) << 2);
}

// Pre-pass: T fp32 [l][k(64)][w(32)] -> bf16 ws, per-leaf [w][k] swizzled.
// LDS-transpose so global reads AND writes are fully coalesced.
__global__ __launch_bounds__(256) void prep_T(const float* __restrict__ T,
                                              __bf16* __restrict__ wsT) {
  __shared__ char tile[4096];
  const int l = blockIdx.x;
  const float* src = T + (size_t)l * 2048;
  const int t = threadIdx.x;
#pragma unroll
  for (int p = 0; p < 2; ++p) {
    int e = p * 1024 + t * 4;  // element within leaf: k = e>>5, w = e&31
    f32x4 v = *(const f32x4*)(src + e);
    int k = e >> 5, w0 = e & 31;
#pragma unroll
    for (int j = 0; j < 4; ++j) {
      int w = w0 + j;
      int off = (w * 128 + 2 * k) ^ ((w & 7) << 4);
      *(__bf16*)(tile + off) = (__bf16)v[j];
    }
  }
  __syncthreads();
  *(uint4v*)((char*)wsT + (size_t)l * 4096 + t * 16) = *(const uint4v*)(tile + t * 16);
}

template <bool USE_WS>
__global__ __launch_bounds__(THREADS, 2)
void prl_main(const float* __restrict__ x, const float* __restrict__ ray,
              const float* __restrict__ w_i, const float* __restrict__ b_i,
              const float* __restrict__ a_i, const void* __restrict__ tsrc,
              float* __restrict__ out) {
  extern __shared__ char smem[];
  const int tid = threadIdx.x;
  const int lane = tid & 63;
  const int wid = tid >> 6;
  const int rg = wid >> 1;   // row-group: 64 rows
  const int cg = wid & 1;    // col-group: 16 cols
  const int g = lane >> 4;
  const int ln = lane & 15;
  const int row0 = blockIdx.x * MBLK;

  float* A_c = (float*)(smem + OFF_AC);
  float* B_c = (float*)(smem + OFF_BC);
  float* angles = (float*)(smem + OFF_ANG);
  float* ray_l = (float*)(smem + OFF_RAY);
  __bf16* distb = (__bf16*)(smem + OFF_DIST);

  // ---- stage node constants + ray ----
  if (tid < 255) {
    float aa = 1.0f + a_i[tid];
    A_c[tid] = (0.5f + sigf(w_i[tid])) * aa;
    B_c[tid] = -sigf(b_i[tid]) * aa;
  }
  if (tid >= 256 && tid < 320) ray_l[tid - 256] = ray[tid - 256];
  __syncthreads();

  // ---- x staging (4 chunks of 64 rows), angles, A-fragment extraction ----
  // wave pair (2c, 2c+1) both extract ALL 64 rows of chunk c (col-split waves).
  bf16x8 afrag[4][2] = {};
  float* xp = (float*)(smem + OFF_XP);
  for (int c = 0; c < 4; ++c) {
    const float* xg = x + (size_t)(row0 + c * 64) * 64;
#pragma unroll
    for (int p = 0; p < 2; ++p) {
      int idx = p * 512 + tid;  // float4 slot 0..1023 in chunk
      f32x4 v = *(const f32x4*)(xg + idx * 4);
      *(f32x4*)(xp + idx * 4) = v;
      int cgr = idx & 15;
      f32x4 rv = *(const f32x4*)(ray_l + cgr * 4);
      float a0 = v[0] * v[0] + v[1] * v[1] + v[2] * v[2] + v[3] * v[3];
      float a1 = v[0] * rv[0] + v[1] * rv[1] + v[2] * rv[2] + v[3] * rv[3];
      float a2 = rv[0] * rv[0] + rv[1] * rv[1] + rv[2] * rv[2] + rv[3] * rv[3];
#pragma unroll
      for (int s = 1; s < 16; s <<= 1) {
        a0 += __shfl_xor(a0, s, 64);
        a1 += __shfl_xor(a1, s, 64);
        a2 += __shfl_xor(a2, s, 64);
      }
      if ((tid & 15) == 0) {
        int r = idx >> 4;
        float xn = fmaxf(sqrtf(a0), 1e-8f);
        float rn = fmaxf(sqrtf(a2), 1e-8f);
        float cs = a1 / (xn * rn);
        cs = fminf(fmaxf(cs, -1.0f), 1.0f);
        angles[c * 64 + r] = acosf(cs) * 0.31830988618379067f;
      }
    }
    __syncthreads();
    if (rg == c) {
#pragma unroll
      for (int mt = 0; mt < 4; ++mt)
#pragma unroll
        for (int kt = 0; kt < 2; ++kt) {
          int rl = mt * 16 + ln;
          int k0 = kt * 32 + g * 8;
          f32x4 u0 = *(const f32x4*)(xp + rl * 64 + k0);
          f32x4 u1 = *(const f32x4*)(xp + rl * 64 + k0 + 4);
          bf16x8 af;
          af[0] = (__bf16)u0[0]; af[1] = (__bf16)u0[1];
          af[2] = (__bf16)u0[2]; af[3] = (__bf16)u0[3];
          af[4] = (__bf16)u1[0]; af[5] = (__bf16)u1[1];
          af[6] = (__bf16)u1[2]; af[7] = (__bf16)u1[3];
          afrag[mt][kt] = af;
        }
    }
    __syncthreads();
  }

  // ---- tree probabilities (level passes, bf16, ping-pong in dead x region) ----
  __bf16* PA = (__bf16*)(smem + OFF_XP);
  __bf16* PB = (__bf16*)(smem + OFF_XP + 8192);
  if (tid < 256) {
    float ang = angles[tid];
    float d = sigf(fmaf(A_c[0], ang, B_c[0]));
    PA[tid] = (__bf16)d;
    PA[256 + tid] = (__bf16)(1.0f - d);
  }
  __syncthreads();
  {
    int n = tid >> 8, r = tid & 255;
    float p = (float)PA[tid];
    float ang = angles[r];
    float d = sigf(fmaf(A_c[1 + n], ang, B_c[1 + n]));
    PB[(2 * n) * 256 + r] = (__bf16)(p * d);
    PB[(2 * n + 1) * 256 + r] = (__bf16)(p * (1.0f - d));
  }
  __syncthreads();
#pragma unroll
  for (int it = 0; it < 2; ++it) {
    int e = it * 512 + tid;
    int n = e >> 8, r = e & 255;
    float p = (float)PB[e];
    float ang = angles[r];
    float d = sigf(fmaf(A_c[3 + n], ang, B_c[3 + n]));
    PA[(2 * n) * 256 + r] = (__bf16)(p * d);
    PA[(2 * n + 1) * 256 + r] = (__bf16)(p * (1.0f - d));
  }
  __syncthreads();
#pragma unroll
  for (int it = 0; it < 4; ++it) {
    int e = it * 512 + tid;
    int n = e >> 8, r = e & 255;
    float p = (float)PA[e];
    float ang = angles[r];
    float d = sigf(fmaf(A_c[7 + n], ang, B_c[7 + n]));
    PB[(2 * n) * 256 + r] = (__bf16)(p * d);
    PB[(2 * n + 1) * 256 + r] = (__bf16)(p * (1.0f - d));
  }
  __syncthreads();
  {
    const int r = tid & 255;
    const int pr = permr(r);
    const float ang = angles[r];
#pragma unroll
    for (int it = 0; it < 8; ++it) {
      int n4 = it * 2 + (tid >> 8);
      float p4 = (float)PB[n4 * 256 + r];
      float d4 = sigf(fmaf(A_c[15 + n4], ang, B_c[15 + n4]));
      float p5[2] = {p4 * d4, p4 * (1.0f - d4)};
#pragma unroll
      for (int b5 = 0; b5 < 2; ++b5) {
        int n5 = 2 * n4 + b5;
        float d5 = sigf(fmaf(A_c[31 + n5], ang, B_c[31 + n5]));
        float p6[2] = {p5[b5] * d5, p5[b5] * (1.0f - d5)};
#pragma unroll
        for (int b6 = 0; b6 < 2; ++b6) {
          int n6 = 2 * n5 + b6;
          float d6 = sigf(fmaf(A_c[63 + n6], ang, B_c[63 + n6]));
          float p7[2] = {p6[b6] * d6, p6[b6] * (1.0f - d6)};
#pragma unroll
          for (int b7 = 0; b7 < 2; ++b7) {
            int n7 = 2 * n6 + b7;
            float d7 = sigf(fmaf(A_c[127 + n7], ang, B_c[127 + n7]));
            float pv = p7[b7];
            distb[(2 * n7) * 256 + pr] = (__bf16)(pv * d7);
            distb[(2 * n7 + 1) * 256 + pr] = (__bf16)(pv * (1.0f - d7));
          }
        }
      }
    }
  }
  __syncthreads();  // dist complete; XP region now dead -> reuse as T dbuf

  // ---- leaf loop ----
  f32x4 acc[4] = {};
  const int wB = cg * 16 + ln;
  const int ad0 = (wB * 128 + g * 16) ^ ((wB & 7) << 4);
  const int ad1 = (wB * 128 + 64 + g * 16) ^ ((wB & 7) << 4);

  auto compute = [&](bf16x8 bk0, bf16x8 bk1, int l) {
    const __bf16* dp = distb + l * 256 + rg * 64 + g * 16;
    bf16x8 q0 = *(const bf16x8*)dp;       // mt0 (e0..3), mt1 (e4..7)
    bf16x8 q1 = *(const bf16x8*)(dp + 8); // mt2, mt3
    f32x4 dv[4];
    dv[0] = (f32x4){(float)q0[0], (float)q0[1], (float)q0[2], (float)q0[3]};
    dv[1] = (f32x4){(float)q0[4], (float)q0[5], (float)q0[6], (float)q0[7]};
    dv[2] = (f32x4){(float)q1[0], (float)q1[1], (float)q1[2], (float)q1[3]};
    dv[3] = (f32x4){(float)q1[4], (float)q1[5], (float)q1[6], (float)q1[7]};
    f32x4 zero = {0.0f, 0.0f, 0.0f, 0.0f};
#pragma unroll
    for (int mt = 0; mt < 4; ++mt) {
      f32x4 y = __builtin_amdgcn_mfma_f32_16x16x32_bf16(afrag[mt][0], bk0, zero, 0, 0, 0);
      y = __builtin_amdgcn_mfma_f32_16x16x32_bf16(afrag[mt][1], bk1, y, 0, 0, 0);
      acc[mt] += dv[mt] * y;
    }
  };

  char* tb = smem + OFF_XP;  // 2 buffers x 8KB (2 leaves each)

  if constexpr (USE_WS) {
    const int ts = tid >> 8;            // which tile of the pair
    const int to = (tid & 255) * 16;    // 16B slot within tile
    uint4v tv = *(const uint4v*)((const char*)tsrc + ts * 4096 + to);
    *(uint4v*)(tb + ts * 4096 + to) = tv;                       // tiles 0,1 -> buf0
    tv = *(const uint4v*)((const char*)tsrc + (2 + ts) * 4096 + to);  // tiles 2,3
    __syncthreads();
    for (int l = 0; l < NLEAF; l += 2) {
      char* cur = tb + ((l >> 1) & 1) * 8192;
      char* nxt = tb + (((l >> 1) + 1) & 1) * 8192;
      if (l + 2 < NLEAF) {
        *(uint4v*)(nxt + ts * 4096 + to) = tv;
        if (l + 4 < NLEAF)
          tv = *(const uint4v*)((const char*)tsrc + (size_t)(l + 4 + ts) * 4096 + to);
      }
      compute(*(const bf16x8*)(cur + ad0), *(const bf16x8*)(cur + ad1), l);
      compute(*(const bf16x8*)(cur + 4096 + ad0), *(const bf16x8*)(cur + 4096 + ad1), l + 1);
      __syncthreads();
    }
  } else {
    for (int l = 0; l < NLEAF; ++l) {
      const float* tp0 = (const float*)tsrc + (size_t)l * 2048 + (g * 8) * 32 + wB;
      const float* tp1 = tp0 + 32 * 32;
      bf16x8 bk0, bk1;
#pragma unroll
      for (int j = 0; j < 8; ++j) {
        bk0[j] = (__bf16)tp0[j * 32];
        bk1[j] = (__bf16)tp1[j * 32];
      }
      compute(bk0, bk1, l);
    }
  }

  // ---- epilogue: C/D layout col=lane&15, row=(lane>>4)*4+reg ----
#pragma unroll
  for (int mt = 0; mt < 4; ++mt)
#pragma unroll
    for (int e = 0; e < 4; ++e) {
      int row = row0 + rg * 64 + mt * 16 + g * 4 + e;
      out[(size_t)row * 32 + cg * 16 + ln] = acc[mt][e];
    }
}

extern "C" void kernel_launch(void* const* d_in, const int* in_sizes, int n_in,
                              void* d_out, int out_size, void* d_ws, size_t ws_size,
                              hipStream_t stream) {
  const float* x = (const float*)d_in[0];
  const float* ray = (const float*)d_in[1];
  const float* T = (const float*)d_in[2];
  const float* w_i = (const float*)d_in[3];
  const float* b_i = (const float*)d_in[4];
  const float* a_i = (const float*)d_in[5];
  float* out = (float*)d_out;

  bool use_ws = ws_size >= (size_t)NLEAF * 4096;
  if (use_ws) {
    hipFuncSetAttribute(reinterpret_cast<const void*>(&prl_main<true>),
                        hipFuncAttributeMaxDynamicSharedMemorySize, SMEM_BYTES);
    prep_T<<<256, 256, 0, stream>>>(T, (__bf16*)d_ws);
    prl_main<true><<<256, THREADS, SMEM_BYTES, stream>>>(x, ray, w_i, b_i, a_i, d_ws, out);
  } else {
    hipFuncSetAttribute(reinterpret_cast<const void*>(&prl_main<false>),
                        hipFuncAttributeMaxDynamicSharedMemorySize, SMEM_BYTES);
    prl_main<false><<<256, THREADS, SMEM_BYTES, stream>>>(x, ray, w_i, b_i, a_i, T, out);
  }
}

// Round 7
// 165.290 us; speedup vs baseline: 1.1420x; 1.0561x over previous
//
#include <hip/hip_runtime.h>
#include <hip/hip_bf16.h>

#define NLEAF 256
#define MBLK 128
#define THREADS 512

typedef __attribute__((ext_vector_type(4))) float f32x4;
typedef __attribute__((ext_vector_type(4))) unsigned int uint4v;
typedef __attribute__((ext_vector_type(8))) __bf16 bf16x8;
typedef __attribute__((ext_vector_type(4))) __bf16 bf16x4;

// LDS layout (bytes), per block = 76544 B -> 2 blocks/CU (160 KiB LDS)
#define OFF_DIST 0      // 65536: dist bf16 [256 leaves][128 perm-rows]; first 32KB = x-stage
#define OFF_T    65536  // 8192 : T dbuf 2x4KB; also tree ping-pong PA/PB
#define OFF_AC   73728  // 1024 : A_c[255]
#define OFF_BC   74752  // 1024 : B_c[255]
#define OFF_ANG  75776  // 512  : angles[128]
#define OFF_RAY  76288  // 256  : ray[64]
#define SMEM_BYTES 76544

__device__ __forceinline__ float sigf(float s) { return 1.0f / (1.0f + __expf(-s)); }

// dist row permutation: row r = rg[6:5] mt[4] g[3:2] e[1:0]  ->  p = rg g mt e
// so one ds_read_b128 at (rg*32+g*8) delivers [mt0 e0..3 | mt1 e0..3].
__device__ __forceinline__ int permr(int r) {
  return (r & 0x63) | ((r & 0x0C) << 1) | ((r & 0x10) >> 2);
}

// Pre-pass: T fp32 [l][k(64)][w(32)] -> bf16 ws, per-leaf [w][k] swizzled.
// LDS-transpose so global reads AND writes are fully coalesced.
__global__ __launch_bounds__(256) void prep_T(const float* __restrict__ T,
                                              __bf16* __restrict__ wsT) {
  __shared__ char tile[4096];
  const int l = blockIdx.x;
  const float* src = T + (size_t)l * 2048;
  const int t = threadIdx.x;
#pragma unroll
  for (int p = 0; p < 2; ++p) {
    int e = p * 1024 + t * 4;  // element within leaf: k = e>>5, w = e&31
    f32x4 v = *(const f32x4*)(src + e);
    int k = e >> 5, w0 = e & 31;
#pragma unroll
    for (int j = 0; j < 4; ++j) {
      int w = w0 + j;
      int off = (w * 128 + 2 * k) ^ ((w & 7) << 4);
      *(__bf16*)(tile + off) = (__bf16)v[j];
    }
  }
  __syncthreads();
  *(uint4v*)((char*)wsT + (size_t)l * 4096 + t * 16) = *(const uint4v*)(tile + t * 16);
}

template <bool USE_WS>
__global__ __launch_bounds__(THREADS, 4)
void prl_main(const float* __restrict__ x, const float* __restrict__ ray,
              const float* __restrict__ w_i, const float* __restrict__ b_i,
              const float* __restrict__ a_i, const void* __restrict__ tsrc,
              float* __restrict__ out) {
  extern __shared__ char smem[];
  const int tid = threadIdx.x;
  const int lane = tid & 63;
  const int wid = tid >> 6;
  const int rg = wid >> 1;   // row-group: 32 rows
  const int cg = wid & 1;    // col-group: 16 cols
  const int g = lane >> 4;
  const int ln = lane & 15;
  const int row0 = blockIdx.x * MBLK;

  float* A_c = (float*)(smem + OFF_AC);
  float* B_c = (float*)(smem + OFF_BC);
  float* angles = (float*)(smem + OFF_ANG);
  float* ray_l = (float*)(smem + OFF_RAY);
  __bf16* distb = (__bf16*)(smem + OFF_DIST);

  // ---- stage node constants + ray ----
  if (tid < 255) {
    float aa = 1.0f + a_i[tid];
    A_c[tid] = (0.5f + sigf(w_i[tid])) * aa;
    B_c[tid] = -sigf(b_i[tid]) * aa;
  }
  if (tid >= 256 && tid < 320) ray_l[tid - 256] = ray[tid - 256];
  __syncthreads();

  // ---- x staging (128 rows = 32KB, fits dist region), angles ----
  float* xp = (float*)(smem + OFF_DIST);
  {
    const float* xg = x + (size_t)row0 * 64;
#pragma unroll
    for (int p = 0; p < 4; ++p) {
      int idx = p * 512 + tid;  // float4 slot 0..2047
      f32x4 v = *(const f32x4*)(xg + idx * 4);
      *(f32x4*)(xp + idx * 4) = v;
      int cgr = idx & 15;
      f32x4 rv = *(const f32x4*)(ray_l + cgr * 4);
      float a0 = v[0] * v[0] + v[1] * v[1] + v[2] * v[2] + v[3] * v[3];
      float a1 = v[0] * rv[0] + v[1] * rv[1] + v[2] * rv[2] + v[3] * rv[3];
      float a2 = rv[0] * rv[0] + rv[1] * rv[1] + rv[2] * rv[2] + rv[3] * rv[3];
#pragma unroll
      for (int s = 1; s < 16; s <<= 1) {
        a0 += __shfl_xor(a0, s, 64);
        a1 += __shfl_xor(a1, s, 64);
        a2 += __shfl_xor(a2, s, 64);
      }
      if ((tid & 15) == 0) {
        int r = idx >> 4;  // 0..127
        float xn = fmaxf(sqrtf(a0), 1e-8f);
        float rn = fmaxf(sqrtf(a2), 1e-8f);
        float cs = a1 / (xn * rn);
        cs = fminf(fmaxf(cs, -1.0f), 1.0f);
        angles[r] = acosf(cs) * 0.31830988618379067f;
      }
    }
  }
  __syncthreads();

  // ---- A-fragment extraction (each wave: its rg's 32 rows, both kt) ----
  bf16x8 afrag[2][2];
#pragma unroll
  for (int mt = 0; mt < 2; ++mt)
#pragma unroll
    for (int kt = 0; kt < 2; ++kt) {
      int rl = rg * 32 + mt * 16 + ln;
      int k0 = kt * 32 + g * 8;
      f32x4 u0 = *(const f32x4*)(xp + rl * 64 + k0);
      f32x4 u1 = *(const f32x4*)(xp + rl * 64 + k0 + 4);
      bf16x8 af;
      af[0] = (__bf16)u0[0]; af[1] = (__bf16)u0[1];
      af[2] = (__bf16)u0[2]; af[3] = (__bf16)u0[3];
      af[4] = (__bf16)u1[0]; af[5] = (__bf16)u1[1];
      af[6] = (__bf16)u1[2]; af[7] = (__bf16)u1[3];
      afrag[mt][kt] = af;
    }
  __syncthreads();  // x region free -> tree may overwrite with dist

  // ---- tree probabilities: ping-pong in T-dbuf area (8KB), rows=128 ----
  __bf16* PA = (__bf16*)(smem + OFF_T);
  __bf16* PB = (__bf16*)(smem + OFF_T + 4096);
  if (tid < 128) {  // P0 -> P1 (2 x 128)
    float ang = angles[tid];
    float d = sigf(fmaf(A_c[0], ang, B_c[0]));
    PA[tid] = (__bf16)d;
    PA[128 + tid] = (__bf16)(1.0f - d);
  }
  __syncthreads();
  if (tid < 256) {  // P1 -> P2 (4 x 128)
    int n = tid >> 7, r = tid & 127;
    float p = (float)PA[tid];
    float ang = angles[r];
    float d = sigf(fmaf(A_c[1 + n], ang, B_c[1 + n]));
    PB[(2 * n) * 128 + r] = (__bf16)(p * d);
    PB[(2 * n + 1) * 128 + r] = (__bf16)(p * (1.0f - d));
  }
  __syncthreads();
  {  // P2 -> P3 (8 x 128)
    int n = tid >> 7, r = tid & 127;
    float p = (float)PB[tid];
    float ang = angles[r];
    float d = sigf(fmaf(A_c[3 + n], ang, B_c[3 + n]));
    PA[(2 * n) * 128 + r] = (__bf16)(p * d);
    PA[(2 * n + 1) * 128 + r] = (__bf16)(p * (1.0f - d));
  }
  __syncthreads();
#pragma unroll
  for (int it = 0; it < 2; ++it) {  // P3 -> P4 (16 x 128)
    int e = it * 512 + tid;
    int n = e >> 7, r = e & 127;
    float p = (float)PA[e];
    float ang = angles[r];
    float d = sigf(fmaf(A_c[7 + n], ang, B_c[7 + n]));
    PB[(2 * n) * 128 + r] = (__bf16)(p * d);
    PB[(2 * n + 1) * 128 + r] = (__bf16)(p * (1.0f - d));
  }
  __syncthreads();
  {  // P4 -> fused levels 4..7 -> dist [leaf][perm-row]
    const int r = tid & 127;
    const int pr = permr(r);
    const float ang = angles[r];
#pragma unroll
    for (int it = 0; it < 4; ++it) {
      int n4 = it * 4 + (tid >> 7);
      float p4 = (float)PB[n4 * 128 + r];
      float d4 = sigf(fmaf(A_c[15 + n4], ang, B_c[15 + n4]));
      float p5[2] = {p4 * d4, p4 * (1.0f - d4)};
#pragma unroll
      for (int b5 = 0; b5 < 2; ++b5) {
        int n5 = 2 * n4 + b5;
        float d5 = sigf(fmaf(A_c[31 + n5], ang, B_c[31 + n5]));
        float p6[2] = {p5[b5] * d5, p5[b5] * (1.0f - d5)};
#pragma unroll
        for (int b6 = 0; b6 < 2; ++b6) {
          int n6 = 2 * n5 + b6;
          float d6 = sigf(fmaf(A_c[63 + n6], ang, B_c[63 + n6]));
          float p7[2] = {p6[b6] * d6, p6[b6] * (1.0f - d6)};
#pragma unroll
          for (int b7 = 0; b7 < 2; ++b7) {
            int n7 = 2 * n6 + b7;
            float d7 = sigf(fmaf(A_c[127 + n7], ang, B_c[127 + n7]));
            float pv = p7[b7];
            distb[(2 * n7) * 128 + pr] = (__bf16)(pv * d7);
            distb[(2 * n7 + 1) * 128 + pr] = (__bf16)(pv * (1.0f - d7));
          }
        }
      }
    }
  }
  // NOTE: no sync here; leaf-loop prologue barrier below covers dist visibility.

  // ---- leaf loop: dbuf T tile, 1 barrier/leaf; per wave: 1 dist b128,
  //      2 B b128, 4 MFMA, 8 cvt + 8 fma ----
  f32x4 acc0 = {}, acc1 = {};
  const int wB = cg * 16 + ln;
  const int ad0 = (wB * 128 + g * 16) ^ ((wB & 7) << 4);
  const int ad1 = (wB * 128 + 64 + g * 16) ^ ((wB & 7) << 4);
  char* tb = smem + OFF_T;

  uint4v tv = {};
  if constexpr (USE_WS) {
    if (tid < 256) {
      tv = *(const uint4v*)((const char*)tsrc + tid * 16);
      // buf0 write must wait until tree's PA/PB use of this area is done:
    }
  }
  __syncthreads();  // tree done (dist visible), T-dbuf area free
  if constexpr (USE_WS) {
    if (tid < 256) {
      *(uint4v*)(tb + tid * 16) = tv;  // tile 0 -> buf0
      tv = *(const uint4v*)((const char*)tsrc + 4096 + tid * 16);  // tile 1
    }
  }
  __syncthreads();  // tile 0 visible

  const f32x4 zero = {0.0f, 0.0f, 0.0f, 0.0f};
  for (int l = 0; l < NLEAF; ++l) {
    char* cur = tb + (l & 1) * 4096;
    char* nxt = tb + ((l + 1) & 1) * 4096;
    if constexpr (USE_WS) {
      if (tid < 256) {
        if (l + 1 < NLEAF) *(uint4v*)(nxt + tid * 16) = tv;
        if (l + 2 < NLEAF)
          tv = *(const uint4v*)((const char*)tsrc + (size_t)(l + 2) * 4096 + tid * 16);
      }
    }
    // dist: one b128, 8 contiguous perm-rows [mt0 e0..3 | mt1 e0..3]
    bf16x8 q = *(const bf16x8*)(distb + l * 128 + rg * 32 + g * 8);
    f32x4 dv0 = (f32x4){(float)q[0], (float)q[1], (float)q[2], (float)q[3]};
    f32x4 dv1 = (f32x4){(float)q[4], (float)q[5], (float)q[6], (float)q[7]};
    bf16x8 b0, b1;
    if constexpr (USE_WS) {
      b0 = *(const bf16x8*)(cur + ad0);
      b1 = *(const bf16x8*)(cur + ad1);
    } else {
      const float* tp0 = (const float*)tsrc + (size_t)l * 2048 + (g * 8) * 32 + wB;
      const float* tp1 = tp0 + 32 * 32;
#pragma unroll
      for (int j = 0; j < 8; ++j) {
        b0[j] = (__bf16)tp0[j * 32];
        b1[j] = (__bf16)tp1[j * 32];
      }
    }
    f32x4 y0 = __builtin_amdgcn_mfma_f32_16x16x32_bf16(afrag[0][0], b0, zero, 0, 0, 0);
    y0 = __builtin_amdgcn_mfma_f32_16x16x32_bf16(afrag[0][1], b1, y0, 0, 0, 0);
    f32x4 y1 = __builtin_amdgcn_mfma_f32_16x16x32_bf16(afrag[1][0], b0, zero, 0, 0, 0);
    y1 = __builtin_amdgcn_mfma_f32_16x16x32_bf16(afrag[1][1], b1, y1, 0, 0, 0);
    acc0 += dv0 * y0;
    acc1 += dv1 * y1;
    if constexpr (USE_WS) __syncthreads();
  }

  // ---- epilogue: C/D layout col=lane&15, row=(lane>>4)*4+reg ----
#pragma unroll
  for (int e = 0; e < 4; ++e) {
    int row = row0 + rg * 32 + g * 4 + e;
    out[(size_t)row * 32 + cg * 16 + ln] = acc0[e];
    out[(size_t)(row + 16) * 32 + cg * 16 + ln] = acc1[e];
  }
}

extern "C" void kernel_launch(void* const* d_in, const int* in_sizes, int n_in,
                              void* d_out, int out_size, void* d_ws, size_t ws_size,
                              hipStream_t stream) {
  const float* x = (const float*)d_in[0];
  const float* ray = (const float*)d_in[1];
  const float* T = (const float*)d_in[2];
  const float* w_i = (const float*)d_in[3];
  const float* b_i = (const float*)d_in[4];
  const float* a_i = (const float*)d_in[5];
  float* out = (float*)d_out;

  const int nblk = 65536 / MBLK;  // 512
  bool use_ws = ws_size >= (size_t)NLEAF * 4096;
  if (use_ws) {
    hipFuncSetAttribute(reinterpret_cast<const void*>(&prl_main<true>),
                        hipFuncAttributeMaxDynamicSharedMemorySize, SMEM_BYTES);
    prep_T<<<256, 256, 0, stream>>>(T, (__bf16*)d_ws);
    prl_main<true><<<nblk, THREADS, SMEM_BYTES, stream>>>(x, ray, w_i, b_i, a_i, d_ws, out);
  } else {
    hipFuncSetAttribute(reinterpret_cast<const void*>(&prl_main<false>),
                        hipFuncAttributeMaxDynamicSharedMemorySize, SMEM_BYTES);
    prl_main<false><<<nblk, THREADS, SMEM_BYTES, stream>>>(x, ray, w_i, b_i, a_i, T, out);
  }
}

// Round 8
// 158.667 us; speedup vs baseline: 1.1896x; 1.0417x over previous
//
#include <hip/hip_runtime.h>
#include <hip/hip_bf16.h>

#define NLEAF 256
#define MBLK 128
#define THREADS 512

typedef __attribute__((ext_vector_type(4))) float f32x4;
typedef __attribute__((ext_vector_type(4))) unsigned int uint4v;
typedef __attribute__((ext_vector_type(8))) __bf16 bf16x8;
typedef __attribute__((ext_vector_type(4))) __bf16 bf16x4;

// LDS layout (bytes), per block = 76544 B -> 2 blocks/CU
#define OFF_DIST 0      // 65536: dist bf16 [256 leaves][128 perm-rows]; first 32KB doubles as x-stage
#define OFF_T    65536  // 8192 : tree ping-pong PA/PB (leaf loop no longer uses LDS for T)
#define OFF_AC   73728  // 1024 : A_c[255]
#define OFF_BC   74752  // 1024 : B_c[255]
#define OFF_ANG  75776  // 512  : angles[128]
#define OFF_RAY  76288  // 256  : ray[64]
#define SMEM_BYTES 76544

__device__ __forceinline__ float sigf(float s) { return 1.0f / (1.0f + __expf(-s)); }

// dist row permutation: row r = rg[6:5] mt[4] g[3:2] e[1:0]  ->  p = rg g mt e
// so one ds_read_b128 at (rg*32+g*8) delivers [mt0 e0..3 | mt1 e0..3].
__device__ __forceinline__ int permr(int r) {
  return (r & 0x63) | ((r & 0x0C) << 1) | ((r & 0x10) >> 2);
}

// Pre-pass: T fp32 [l][k(64)][w(32)] -> bf16 ws in cg-major MFMA FRAGMENT ORDER:
// off(k,w) = (w>>4)*2048 + (k>>5)*1024 + (((k>>3)&3)*16 + (w&15))*16 + (k&7)*2
// so a wave (cg) reads leaf l's two fragments at l*4096 + cg*2048 + {0,1024} + lane*16.
// LDS-transpose keeps global reads AND writes fully coalesced.
__global__ __launch_bounds__(256) void prep_T(const float* __restrict__ T,
                                              __bf16* __restrict__ wsT) {
  __shared__ char tile[4096];
  const int l = blockIdx.x;
  const float* src = T + (size_t)l * 2048;
  const int t = threadIdx.x;
#pragma unroll
  for (int p = 0; p < 2; ++p) {
    int e = p * 1024 + t * 4;  // element within leaf: k = e>>5, w = e&31
    f32x4 v = *(const f32x4*)(src + e);
    int k = e >> 5, w0 = e & 31;
#pragma unroll
    for (int j = 0; j < 4; ++j) {
      int w = w0 + j;
      int off = (w >> 4) * 2048 + (k >> 5) * 1024 +
                (((k >> 3) & 3) * 16 + (w & 15)) * 16 + (k & 7) * 2;
      *(__bf16*)(tile + off) = (__bf16)v[j];
    }
  }
  __syncthreads();
  *(uint4v*)((char*)wsT + (size_t)l * 4096 + t * 16) = *(const uint4v*)(tile + t * 16);
}

template <bool USE_WS>
__global__ __launch_bounds__(THREADS, 4)
void prl_main(const float* __restrict__ x, const float* __restrict__ ray,
              const float* __restrict__ w_i, const float* __restrict__ b_i,
              const float* __restrict__ a_i, const void* __restrict__ tsrc,
              float* __restrict__ out) {
  extern __shared__ char smem[];
  const int tid = threadIdx.x;
  const int lane = tid & 63;
  const int wid = tid >> 6;
  const int rg = wid >> 1;   // row-group: 32 rows
  const int cg = wid & 1;    // col-group: 16 cols
  const int g = lane >> 4;
  const int ln = lane & 15;
  const int row0 = blockIdx.x * MBLK;

  float* A_c = (float*)(smem + OFF_AC);
  float* B_c = (float*)(smem + OFF_BC);
  float* angles = (float*)(smem + OFF_ANG);
  float* ray_l = (float*)(smem + OFF_RAY);
  __bf16* distb = (__bf16*)(smem + OFF_DIST);

  // ---- stage node constants + ray ----
  if (tid < 255) {
    float aa = 1.0f + a_i[tid];
    A_c[tid] = (0.5f + sigf(w_i[tid])) * aa;
    B_c[tid] = -sigf(b_i[tid]) * aa;
  }
  if (tid >= 256 && tid < 320) ray_l[tid - 256] = ray[tid - 256];
  __syncthreads();

  // ---- x staging (128 rows = 32KB in dist region), angles ----
  float* xp = (float*)(smem + OFF_DIST);
  {
    const float* xg = x + (size_t)row0 * 64;
#pragma unroll
    for (int p = 0; p < 4; ++p) {
      int idx = p * 512 + tid;  // float4 slot 0..2047
      f32x4 v = *(const f32x4*)(xg + idx * 4);
      *(f32x4*)(xp + idx * 4) = v;
      int cgr = idx & 15;
      f32x4 rv = *(const f32x4*)(ray_l + cgr * 4);
      float a0 = v[0] * v[0] + v[1] * v[1] + v[2] * v[2] + v[3] * v[3];
      float a1 = v[0] * rv[0] + v[1] * rv[1] + v[2] * rv[2] + v[3] * rv[3];
      float a2 = rv[0] * rv[0] + rv[1] * rv[1] + rv[2] * rv[2] + rv[3] * rv[3];
#pragma unroll
      for (int s = 1; s < 16; s <<= 1) {
        a0 += __shfl_xor(a0, s, 64);
        a1 += __shfl_xor(a1, s, 64);
        a2 += __shfl_xor(a2, s, 64);
      }
      if ((tid & 15) == 0) {
        int r = idx >> 4;  // 0..127
        float xn = fmaxf(sqrtf(a0), 1e-8f);
        float rn = fmaxf(sqrtf(a2), 1e-8f);
        float cs = a1 / (xn * rn);
        cs = fminf(fmaxf(cs, -1.0f), 1.0f);
        angles[r] = acosf(cs) * 0.31830988618379067f;
      }
    }
  }
  __syncthreads();

  // ---- A-fragment extraction (each wave: its rg's 32 rows, both kt) ----
  bf16x8 afrag[2][2];
#pragma unroll
  for (int mt = 0; mt < 2; ++mt)
#pragma unroll
    for (int kt = 0; kt < 2; ++kt) {
      int rl = rg * 32 + mt * 16 + ln;
      int k0 = kt * 32 + g * 8;
      f32x4 u0 = *(const f32x4*)(xp + rl * 64 + k0);
      f32x4 u1 = *(const f32x4*)(xp + rl * 64 + k0 + 4);
      bf16x8 af;
      af[0] = (__bf16)u0[0]; af[1] = (__bf16)u0[1];
      af[2] = (__bf16)u0[2]; af[3] = (__bf16)u0[3];
      af[4] = (__bf16)u1[0]; af[5] = (__bf16)u1[1];
      af[6] = (__bf16)u1[2]; af[7] = (__bf16)u1[3];
      afrag[mt][kt] = af;
    }
  __syncthreads();  // x region free -> tree may overwrite with dist

  // ---- tree probabilities: ping-pong in OFF_T area (8KB), rows=128 ----
  __bf16* PA = (__bf16*)(smem + OFF_T);
  __bf16* PB = (__bf16*)(smem + OFF_T + 4096);
  if (tid < 128) {  // P0 -> P1 (2 x 128)
    float ang = angles[tid];
    float d = sigf(fmaf(A_c[0], ang, B_c[0]));
    PA[tid] = (__bf16)d;
    PA[128 + tid] = (__bf16)(1.0f - d);
  }
  __syncthreads();
  if (tid < 256) {  // P1 -> P2 (4 x 128)
    int n = tid >> 7, r = tid & 127;
    float p = (float)PA[tid];
    float ang = angles[r];
    float d = sigf(fmaf(A_c[1 + n], ang, B_c[1 + n]));
    PB[(2 * n) * 128 + r] = (__bf16)(p * d);
    PB[(2 * n + 1) * 128 + r] = (__bf16)(p * (1.0f - d));
  }
  __syncthreads();
  {  // P2 -> P3 (8 x 128)
    int n = tid >> 7, r = tid & 127;
    float p = (float)PB[tid];
    float ang = angles[r];
    float d = sigf(fmaf(A_c[3 + n], ang, B_c[3 + n]));
    PA[(2 * n) * 128 + r] = (__bf16)(p * d);
    PA[(2 * n + 1) * 128 + r] = (__bf16)(p * (1.0f - d));
  }
  __syncthreads();
#pragma unroll
  for (int it = 0; it < 2; ++it) {  // P3 -> P4 (16 x 128)
    int e = it * 512 + tid;
    int n = e >> 7, r = e & 127;
    float p = (float)PA[e];
    float ang = angles[r];
    float d = sigf(fmaf(A_c[7 + n], ang, B_c[7 + n]));
    PB[(2 * n) * 128 + r] = (__bf16)(p * d);
    PB[(2 * n + 1) * 128 + r] = (__bf16)(p * (1.0f - d));
  }
  __syncthreads();
  {  // P4 -> fused levels 4..7 -> dist [leaf][perm-row]
    const int r = tid & 127;
    const int pr = permr(r);
    const float ang = angles[r];
#pragma unroll
    for (int it = 0; it < 4; ++it) {
      int n4 = it * 4 + (tid >> 7);
      float p4 = (float)PB[n4 * 128 + r];
      float d4 = sigf(fmaf(A_c[15 + n4], ang, B_c[15 + n4]));
      float p5[2] = {p4 * d4, p4 * (1.0f - d4)};
#pragma unroll
      for (int b5 = 0; b5 < 2; ++b5) {
        int n5 = 2 * n4 + b5;
        float d5 = sigf(fmaf(A_c[31 + n5], ang, B_c[31 + n5]));
        float p6[2] = {p5[b5] * d5, p5[b5] * (1.0f - d5)};
#pragma unroll
        for (int b6 = 0; b6 < 2; ++b6) {
          int n6 = 2 * n5 + b6;
          float d6 = sigf(fmaf(A_c[63 + n6], ang, B_c[63 + n6]));
          float p7[2] = {p6[b6] * d6, p6[b6] * (1.0f - d6)};
#pragma unroll
          for (int b7 = 0; b7 < 2; ++b7) {
            int n7 = 2 * n6 + b7;
            float d7 = sigf(fmaf(A_c[127 + n7], ang, B_c[127 + n7]));
            float pv = p7[b7];
            distb[(2 * n7) * 128 + pr] = (__bf16)(pv * d7);
            distb[(2 * n7 + 1) * 128 + pr] = (__bf16)(pv * (1.0f - d7));
          }
        }
      }
    }
  }
  __syncthreads();  // dist visible; NO barriers from here on — waves free-run

  // ---- leaf loop: B direct global->VGPR (cg-major fragment order),
  //      4 register sets, prefetch distance 2 leaves, barrier-free ----
  f32x4 acc0 = {}, acc1 = {};
  const f32x4 zero = {0.0f, 0.0f, 0.0f, 0.0f};
  const __bf16* dbase = distb + rg * 32 + g * 8;

#define COMPUTE(B0, B1, L)                                                         \
  {                                                                                \
    bf16x8 q = *(const bf16x8*)(dbase + (L) * 128);                                \
    f32x4 dv0 = (f32x4){(float)q[0], (float)q[1], (float)q[2], (float)q[3]};       \
    f32x4 dv1 = (f32x4){(float)q[4], (float)q[5], (float)q[6], (float)q[7]};       \
    f32x4 y0 = __builtin_amdgcn_mfma_f32_16x16x32_bf16(afrag[0][0], B0, zero, 0, 0, 0); \
    y0 = __builtin_amdgcn_mfma_f32_16x16x32_bf16(afrag[0][1], B1, y0, 0, 0, 0);    \
    f32x4 y1 = __builtin_amdgcn_mfma_f32_16x16x32_bf16(afrag[1][0], B0, zero, 0, 0, 0); \
    y1 = __builtin_amdgcn_mfma_f32_16x16x32_bf16(afrag[1][1], B1, y1, 0, 0, 0);    \
    acc0 += dv0 * y0;                                                              \
    acc1 += dv1 * y1;                                                              \
  }

  if constexpr (USE_WS) {
    const char* bp = (const char*)tsrc + cg * 2048 + (size_t)lane * 16;
    bf16x8 s0a, s0b, s1a, s1b, s2a, s2b, s3a, s3b;
    s0a = *(const bf16x8*)(bp);
    s0b = *(const bf16x8*)(bp + 1024);
    s1a = *(const bf16x8*)(bp + 4096);
    s1b = *(const bf16x8*)(bp + 4096 + 1024);
    for (int l = 0; l < NLEAF; l += 4) {
      {  // issue leaf l+2 -> set2
        const char* q = bp + (size_t)(l + 2) * 4096;
        s2a = *(const bf16x8*)(q);
        s2b = *(const bf16x8*)(q + 1024);
      }
      COMPUTE(s0a, s0b, l);
      {  // issue leaf l+3 -> set3
        const char* q = bp + (size_t)(l + 3) * 4096;
        s3a = *(const bf16x8*)(q);
        s3b = *(const bf16x8*)(q + 1024);
      }
      COMPUTE(s1a, s1b, l + 1);
      if (l + 4 < NLEAF) {  // issue leaf l+4 -> set0
        const char* q = bp + (size_t)(l + 4) * 4096;
        s0a = *(const bf16x8*)(q);
        s0b = *(const bf16x8*)(q + 1024);
      }
      COMPUTE(s2a, s2b, l + 2);
      if (l + 5 < NLEAF) {  // issue leaf l+5 -> set1
        const char* q = bp + (size_t)(l + 5) * 4096;
        s1a = *(const bf16x8*)(q);
        s1b = *(const bf16x8*)(q + 1024);
      }
      COMPUTE(s3a, s3b, l + 3);
    }
  } else {
    const int wB = cg * 16 + ln;
    for (int l = 0; l < NLEAF; ++l) {
      const float* tp0 = (const float*)tsrc + (size_t)l * 2048 + (g * 8) * 32 + wB;
      const float* tp1 = tp0 + 32 * 32;
      bf16x8 b0, b1;
#pragma unroll
      for (int j = 0; j < 8; ++j) {
        b0[j] = (__bf16)tp0[j * 32];
        b1[j] = (__bf16)tp1[j * 32];
      }
      COMPUTE(b0, b1, l);
    }
  }
#undef COMPUTE

  // ---- epilogue: C/D layout col=lane&15, row=(lane>>4)*4+reg ----
#pragma unroll
  for (int e = 0; e < 4; ++e) {
    int row = row0 + rg * 32 + g * 4 + e;
    out[(size_t)row * 32 + cg * 16 + ln] = acc0[e];
    out[(size_t)(row + 16) * 32 + cg * 16 + ln] = acc1[e];
  }
}

extern "C" void kernel_launch(void* const* d_in, const int* in_sizes, int n_in,
                              void* d_out, int out_size, void* d_ws, size_t ws_size,
                              hipStream_t stream) {
  const float* x = (const float*)d_in[0];
  const float* ray = (const float*)d_in[1];
  const float* T = (const float*)d_in[2];
  const float* w_i = (const float*)d_in[3];
  const float* b_i = (const float*)d_in[4];
  const float* a_i = (const float*)d_in[5];
  float* out = (float*)d_out;

  const int nblk = 65536 / MBLK;  // 512
  bool use_ws = ws_size >= (size_t)NLEAF * 4096;
  if (use_ws) {
    hipFuncSetAttribute(reinterpret_cast<const void*>(&prl_main<true>),
                        hipFuncAttributeMaxDynamicSharedMemorySize, SMEM_BYTES);
    prep_T<<<256, 256, 0, stream>>>(T, (__bf16*)d_ws);
    prl_main<true><<<nblk, THREADS, SMEM_BYTES, stream>>>(x, ray, w_i, b_i, a_i, d_ws, out);
  } else {
    hipFuncSetAttribute(reinterpret_cast<const void*>(&prl_main<false>),
                        hipFuncAttributeMaxDynamicSharedMemorySize, SMEM_BYTES);
    prl_main<false><<<nblk, THREADS, SMEM_BYTES, stream>>>(x, ray, w_i, b_i, a_i, T, out);
  }
}